// Round 13
// baseline (377.239 us; speedup 1.0000x reference)
//
#include <hip/hip_runtime.h>
#include <hip/hip_bf16.h>
#include <math.h>

typedef short short8 __attribute__((ext_vector_type(8)));
typedef float f32x4  __attribute__((ext_vector_type(4)));
typedef unsigned int u32;

#define B_ROWS 8192
#define IN_DIM 1024
#define OUT_DIM 256
#define M_DIM 1280
#define P_DIM 2304
#define NJ 10
#define RB 16                  // rows per block -> 512 blocks, 2 blocks/CU, 16 waves/CU
#define BK 64
#define HG_COLS 1152

// ws: Xbf bf16[8192][1024] ; Wbf bf16[1280][2304] ; Hg bf16[8192][1152]
#define WBF_OFF (B_ROWS * (size_t)IN_DIM * 2)
#define HG_OFF  (WBF_OFF + (size_t)M_DIM * P_DIM * 2)

__device__ __forceinline__ short f2bf(float x)
{
    __hip_bfloat16 h = __float2bfloat16(x);
    return *(short*)&h;
}

__device__ __forceinline__ float tanh_fast(float x)
{
    x = fminf(fmaxf(x, -15.f), 15.f);
    float e = __expf(2.f * x);
    return (e - 1.f) * __builtin_amdgcn_rcpf(e + 1.f);
}

__global__ __launch_bounds__(256)
void convert_x(const float* __restrict__ x, short* __restrict__ Xbf)
{
    int idx = blockIdx.x * 256 + threadIdx.x;
    int r  = idx >> 7;
    int c8 = (idx & 127) << 3;
    const float* src = x + (size_t)r * IN_DIM + c8;
    float4 a0 = *(const float4*)src;
    float4 a1 = *(const float4*)(src + 4);
    short8 s;
    s[0] = f2bf(a0.x); s[1] = f2bf(a0.y); s[2] = f2bf(a0.z); s[3] = f2bf(a0.w);
    s[4] = f2bf(a1.x); s[5] = f2bf(a1.y); s[6] = f2bf(a1.z); s[7] = f2bf(a1.w);
    *(short8*)(Xbf + (size_t)r * IN_DIM + c8) = s;
}

__global__ __launch_bounds__(256)
void convert_w(const float* __restrict__ W, short* __restrict__ Wbf)
{
    size_t e8 = ((size_t)blockIdx.x * 256 + threadIdx.x) * 8;
    float4 a0 = *(const float4*)(W + e8);
    float4 a1 = *(const float4*)(W + e8 + 4);
    short8 s;
    s[0] = f2bf(a0.x); s[1] = f2bf(a0.y); s[2] = f2bf(a0.z); s[3] = f2bf(a0.w);
    s[4] = f2bf(a1.x); s[5] = f2bf(a1.y); s[6] = f2bf(a1.z); s[7] = f2bf(a1.w);
    *(short8*)(Wbf + e8) = s;
}

// LDS union (76,032 B):
//  GEMM: xs[2] @0/@2048 ; Wst[2] @4096/@20480 (ends 36,864)  [XOR-swizzled]
//  seq : PreL f32[16][132] @0 (8,448) ; lwf f32[128][132] @8448 (67,584)
#define LWF_OFF 8448
#define PLS 132
#define LWS 132

__global__ __launch_bounds__(512, 4)
void fused(const short* __restrict__ Xbf, const short* __restrict__ Wbf,
           const float* __restrict__ Wf, short* __restrict__ Hg,
           const float* __restrict__ bias, float* __restrict__ out)
{
    __shared__ __align__(16) char L[76032];

    const int tid  = threadIdx.x;
    const int lane = tid & 63;
    const int w    = tid >> 6;      // wave 0..7
    const int fr   = lane & 15;     // GEMM fragment row/col
    const int fq   = lane >> 4;     // GEMM k-quarter
    const int r2   = lane & 1;      // seq: row within wave's 2
    const int sl   = (lane >> 1) & 15;  // seq: slice 0..15 (8 u's)
    const int dup  = lane >> 5;     // seq: duplicate half
    const int srow = w * 2 + r2;    // seq row in block
    const int bm   = blockIdx.x * RB;
    const int sa_r  = tid >> 3;         // A staging (tid<128)
    const int sa_k8 = (tid & 7) << 3;

#pragma unroll 1
    for (int J = 0; J < NJ; ++J) {
        const int j0 = J * 128;
        const int nt = (IN_DIM + j0) / BK;

        f32x4 acc = {0.f, 0.f, 0.f, 0.f};

        __syncthreads();   // prev J fully done (lwf/PreL reads finished)

        short8 ra; short8 rw[2];
        {
            if (tid < 128)
                ra = *(const short8*)(Xbf + (size_t)(bm + sa_r) * IN_DIM + sa_k8);
#pragma unroll
            for (int c = 0; c < 2; ++c) {
                int idx = tid + c * 512;
                int n = idx >> 3, k8 = (idx & 7) << 3;
                rw[c] = *(const short8*)(Wbf + (size_t)(j0 + n) * P_DIM + k8);
            }
            if (tid < 128)
                *(short8*)(L + ((sa_r * 128 + sa_k8 * 2) ^ ((sa_r & 7) << 4))) = ra;
#pragma unroll
            for (int c = 0; c < 2; ++c) {
                int idx = tid + c * 512;
                int n = idx >> 3, k8 = (idx & 7) << 3;
                *(short8*)(L + 4096 + ((n * 128 + k8 * 2) ^ ((n & 7) << 4))) = rw[c];
            }
        }

#pragma unroll 1
        for (int t = 0; t < nt; ++t) {
            if (t + 1 < nt) {
                int k0 = (t + 1) * BK;
                if (tid < 128) {
                    const short* src = (k0 < IN_DIM)
                        ? (Xbf + (size_t)(bm + sa_r) * IN_DIM + k0 + sa_k8)
                        : (Hg + (size_t)(bm + sa_r) * HG_COLS + (k0 - IN_DIM) + sa_k8);
                    ra = *(const short8*)src;
                }
#pragma unroll
                for (int c = 0; c < 2; ++c) {
                    int idx = tid + c * 512;
                    int n = idx >> 3, k8 = (idx & 7) << 3;
                    rw[c] = *(const short8*)(Wbf + (size_t)(j0 + n) * P_DIM + k0 + k8);
                }
            }
            __syncthreads();
            const char* xb = L + (t & 1) * 2048;
            const char* wb = L + 4096 + (t & 1) * 16384;
            const int n0 = w * 16 + fr;
#pragma unroll
            for (int k32 = 0; k32 < 2; ++k32) {
                int kb = k32 * 64 + fq * 16;
                short8 a = *(const short8*)(xb + ((fr * 128 + kb) ^ ((fr & 7) << 4)));
                short8 b = *(const short8*)(wb + ((n0 * 128 + kb) ^ ((n0 & 7) << 4)));
                acc = __builtin_amdgcn_mfma_f32_16x16x32_bf16(a, b, acc, 0, 0, 0);
            }
            if (t + 1 < nt) {
                char* xw = L + ((t + 1) & 1) * 2048;
                char* ww = L + 4096 + ((t + 1) & 1) * 16384;
                if (tid < 128)
                    *(short8*)(xw + ((sa_r * 128 + sa_k8 * 2) ^ ((sa_r & 7) << 4))) = ra;
#pragma unroll
                for (int c = 0; c < 2; ++c) {
                    int idx = tid + c * 512;
                    int n = idx >> 3, k8 = (idx & 7) << 3;
                    *(short8*)(ww + ((n * 128 + k8 * 2) ^ ((n & 7) << 4))) = rw[c];
                }
            }
        }
        __syncthreads();   // MFMAs done; LDS free for seq overlay

        // ---- epilogue: PreL = acc + bias; stage lwf f32 (tri-zeroed) ------
        {
            float* PreL = (float*)L;
            float bv = bias[j0 + w * 16 + fr];
#pragma unroll
            for (int r = 0; r < 4; ++r)
                PreL[(fq * 4 + r) * PLS + w * 16 + fr] = acc[r] + bv;

            float* lwf = (float*)(L + LWF_OFF);
            int u = tid & 127, th = tid >> 7;     // th 0..3
#pragma unroll
            for (int it = 0; it < 8; ++it) {
                int t4 = (it * 4 + th) * 4;
                float4 v = *(const float4*)(Wf + (size_t)(j0 + u) * P_DIM + IN_DIM + j0 + t4);
                lwf[(t4 + 0) * LWS + u] = (u > t4 + 0) ? v.x : 0.f;
                lwf[(t4 + 1) * LWS + u] = (u > t4 + 1) ? v.y : 0.f;
                lwf[(t4 + 2) * LWS + u] = (u > t4 + 2) ? v.z : 0.f;
                lwf[(t4 + 3) * LWS + u] = (u > t4 + 3) ? v.w : 0.f;
            }
        }
        __syncthreads();

        float as[8];
        {
            const float* pr = (const float*)L + srow * PLS + sl * 8;
            f32x4 v0 = *(const f32x4*)pr;
            f32x4 v1 = *(const f32x4*)(pr + 4);
            as[0] = v0[0]; as[1] = v0[1]; as[2] = v0[2]; as[3] = v0[3];
            as[4] = v1[0]; as[5] = v1[1]; as[6] = v1[2]; as[7] = v1[3];
        }

        // ---- seq: 16 groups of 8; micro-triangle + bpermute burst ---------
        const float* lwf = (const float*)(L + LWF_OFF);
#pragma unroll 1
        for (int g = 0; g < 16; ++g) {
            const int  hsrc = r2 | (g << 1) | (dup << 5);   // intra-wave owner
            const bool own  = (sl == g);

            f32x4 wq[16];
#pragma unroll
            for (int s = 0; s < 8; ++s) {
                const float* wr_ = lwf + (g * 8 + s) * LWS + sl * 8;
                wq[2 * s]     = *(const f32x4*)wr_;
                wq[2 * s + 1] = *(const f32x4*)(wr_ + 4);
            }

            float tt[8], hh[8];
#pragma unroll
            for (int e = 0; e < 8; ++e) tt[e] = as[e];
#pragma unroll
            for (int s = 0; s < 8; ++s) {
                hh[s] = tanh_fast(tt[s]);
#pragma unroll
                for (int e = s + 1; e < 8; ++e) {
                    float wv = (e < 4) ? wq[2 * s][e] : wq[2 * s + 1][e - 4];
                    tt[e] += wv * hh[s];
                }
            }

            float hb[8];
#pragma unroll
            for (int s = 0; s < 8; ++s) hb[s] = __shfl(hh[s], hsrc);

#pragma unroll
            for (int e = 0; e < 8; ++e) {
                float v = as[e];
#pragma unroll
                for (int s = 0; s < 8; ++s) {
                    float wv = (e < 4) ? wq[2 * s][e] : wq[2 * s + 1][e - 4];
                    v += wv * hb[s];
                }
                as[e] = own ? hb[e] : v;
            }
        }

        // ---- write h to global H panel / output (dup 0 only) --------------
        if (dup == 0) {
            if (J < 9) {
                short8 hv;
#pragma unroll
                for (int e = 0; e < 8; ++e) hv[e] = f2bf(as[e]);
                *(short8*)(Hg + (size_t)(bm + srow) * HG_COLS + j0 + sl * 8) = hv;
            }
            if (J >= 8) {
                float* op = out + (size_t)(bm + srow) * OUT_DIM + (j0 - IN_DIM) + sl * 8;
                float4 o0, o1;
                o0.x = 1.f / (1.f + __expf(-as[0]));
                o0.y = 1.f / (1.f + __expf(-as[1]));
                o0.z = 1.f / (1.f + __expf(-as[2]));
                o0.w = 1.f / (1.f + __expf(-as[3]));
                o1.x = 1.f / (1.f + __expf(-as[4]));
                o1.y = 1.f / (1.f + __expf(-as[5]));
                o1.z = 1.f / (1.f + __expf(-as[6]));
                o1.w = 1.f / (1.f + __expf(-as[7]));
                *(float4*)op = o0;
                *(float4*)(op + 4) = o1;
            }
        }
    }
}

extern "C" void kernel_launch(void* const* d_in, const int* in_sizes, int n_in,
                              void* d_out, int out_size, void* d_ws, size_t ws_size,
                              hipStream_t stream)
{
    const float* x    = (const float*)d_in[0];
    const float* W    = (const float*)d_in[1];
    const float* bias = (const float*)d_in[2];
    float* out = (float*)d_out;
    short* Xbf = (short*)d_ws;
    short* Wbf = (short*)((char*)d_ws + WBF_OFF);
    short* Hg  = (short*)((char*)d_ws + HG_OFF);

    convert_x<<<dim3(B_ROWS * IN_DIM / 8 / 256), dim3(256), 0, stream>>>(x, Xbf);
    convert_w<<<dim3(M_DIM * P_DIM / 8 / 256), dim3(256), 0, stream>>>(W, Wbf);
    fused<<<dim3(B_ROWS / RB), dim3(512), 0, stream>>>(Xbf, Wbf, W, Hg, bias, out);
}

// Round 14
// 304.399 us; speedup vs baseline: 1.2393x; 1.2393x over previous
//
#include <hip/hip_runtime.h>
#include <hip/hip_bf16.h>
#include <math.h>

typedef short short8 __attribute__((ext_vector_type(8)));
typedef float f32x4  __attribute__((ext_vector_type(4)));
typedef unsigned int u32;

#define B_ROWS 8192
#define IN_DIM 1024
#define OUT_DIM 256
#define M_DIM 1280
#define P_DIM 2304
#define NJ 10
#define RB 16                  // rows per block -> 512 blocks
#define BK 64
#define HG_COLS 1152

// ws: Xbf bf16[8192][1024] ; Wbf bf16[1280][2304] ; Hg bf16[8192][1152]
#define WBF_OFF (B_ROWS * (size_t)IN_DIM * 2)
#define HG_OFF  (WBF_OFF + (size_t)M_DIM * P_DIM * 2)

__device__ __forceinline__ short f2bf(float x)
{
    __hip_bfloat16 h = __float2bfloat16(x);
    return *(short*)&h;
}

// tanh = 1 - 2/(e^{2x}+1); saturates correctly at +-inf, no clamp needed.
__device__ __forceinline__ float tanh_fast(float x)
{
    float e = __expf(2.f * x);
    return 1.f - 2.f * __builtin_amdgcn_rcpf(e + 1.f);
}

__device__ __forceinline__ float sigmoid_fast(float y)
{
    return __builtin_amdgcn_rcpf(1.f + __expf(-y));
}

__global__ __launch_bounds__(256)
void convert_x(const float* __restrict__ x, short* __restrict__ Xbf)
{
    int idx = blockIdx.x * 256 + threadIdx.x;
    int r  = idx >> 7;
    int c8 = (idx & 127) << 3;
    const float* src = x + (size_t)r * IN_DIM + c8;
    float4 a0 = *(const float4*)src;
    float4 a1 = *(const float4*)(src + 4);
    short8 s;
    s[0] = f2bf(a0.x); s[1] = f2bf(a0.y); s[2] = f2bf(a0.z); s[3] = f2bf(a0.w);
    s[4] = f2bf(a1.x); s[5] = f2bf(a1.y); s[6] = f2bf(a1.z); s[7] = f2bf(a1.w);
    *(short8*)(Xbf + (size_t)r * IN_DIM + c8) = s;
}

__global__ __launch_bounds__(256)
void convert_w(const float* __restrict__ W, short* __restrict__ Wbf)
{
    size_t e8 = ((size_t)blockIdx.x * 256 + threadIdx.x) * 8;
    float4 a0 = *(const float4*)(W + e8);
    float4 a1 = *(const float4*)(W + e8 + 4);
    short8 s;
    s[0] = f2bf(a0.x); s[1] = f2bf(a0.y); s[2] = f2bf(a0.z); s[3] = f2bf(a0.w);
    s[4] = f2bf(a1.x); s[5] = f2bf(a1.y); s[6] = f2bf(a1.z); s[7] = f2bf(a1.w);
    *(short8*)(Wbf + e8) = s;
}

// LDS union (43,264 B):
//  GEMM: xbuf[2] @0/@2048 (16x64 bf16, XOR-swz) ; wbuf[2] @4096/@20480 (128x64)
//  seq : PreL f32[16][132] @0 (8,448) ; lwf bf16[128][136] @8448 (34,816)
#define LWF_OFF 8448
#define PLS 132
#define LWS 136

__global__ __launch_bounds__(256, 3)
void fused(const short* __restrict__ Xbf, const short* __restrict__ Wbf,
           short* __restrict__ Hg, const float* __restrict__ bias,
           float* __restrict__ out)
{
    __shared__ __align__(16) char L[43264];

    const int tid  = threadIdx.x;
    const int lane = tid & 63;
    const int w    = tid >> 6;      // wave 0..3
    const int fr   = lane & 15;     // GEMM fragment row/col
    const int fq   = lane >> 4;     // GEMM k-quarter
    const int r4   = lane & 3;      // seq: row within wave's 4
    const int sl   = lane >> 2;     // seq: slice 0..15 (8 u's)
    const int srow = w * 4 + r4;    // seq row in block
    const int bm   = blockIdx.x * RB;
    const int sa_r  = tid >> 3;         // A staging (tid<128)
    const int sa_k8 = (tid & 7) << 3;
    const int n0 = w * 32 + fr;
    const int n1 = n0 + 16;

#pragma unroll 1
    for (int J = 0; J < NJ; ++J) {
        const int j0 = J * 128;
        const int nt = (IN_DIM + j0) / BK;   // always even (16 + 2J)

        f32x4 acc0 = {0.f, 0.f, 0.f, 0.f};
        f32x4 acc1 = {0.f, 0.f, 0.f, 0.f};

        __syncthreads();   // prev J fully done (lwf/PreL reads finished)

        auto issue = [&](short8& ra, short8 (&rw)[4], int k0) {
            if (tid < 128) {
                const short* s = (k0 < IN_DIM)
                    ? (Xbf + (size_t)(bm + sa_r) * IN_DIM + k0 + sa_k8)
                    : (Hg + (size_t)(bm + sa_r) * HG_COLS + (k0 - IN_DIM) + sa_k8);
                ra = *(const short8*)s;
            }
#pragma unroll
            for (int c = 0; c < 4; ++c) {
                int idx = tid + c * 256;
                int n = idx >> 3, k8 = (idx & 7) << 3;
                rw[c] = *(const short8*)(Wbf + (size_t)(j0 + n) * P_DIM + k0 + k8);
            }
        };
        auto lwrite = [&](short8& ra, short8 (&rw)[4], char* xw, char* ww) {
            if (tid < 128)
                *(short8*)(xw + ((sa_r * 128 + sa_k8 * 2) ^ ((sa_r & 7) << 4))) = ra;
#pragma unroll
            for (int c = 0; c < 4; ++c) {
                int idx = tid + c * 256;
                int n = idx >> 3, k8 = (idx & 7) << 3;
                *(short8*)(ww + ((n * 128 + k8 * 2) ^ ((n & 7) << 4))) = rw[c];
            }
        };
        auto domfma = [&](const char* xb, const char* wb) {
#pragma unroll
            for (int k32 = 0; k32 < 2; ++k32) {
                int kb = k32 * 64 + fq * 16;
                short8 a  = *(const short8*)(xb + ((fr * 128 + kb) ^ ((fr & 7) << 4)));
                short8 b0 = *(const short8*)(wb + ((n0 * 128 + kb) ^ ((n0 & 7) << 4)));
                short8 b1 = *(const short8*)(wb + ((n1 * 128 + kb) ^ ((n1 & 7) << 4)));
                acc0 = __builtin_amdgcn_mfma_f32_16x16x32_bf16(a, b0, acc0, 0, 0, 0);
                acc1 = __builtin_amdgcn_mfma_f32_16x16x32_bf16(a, b1, acc1, 0, 0, 0);
            }
        };

        // ---- depth-2 pipelined GEMM ---------------------------------------
        short8 ra0, ra1; short8 rw0[4], rw1[4];
        issue(ra0, rw0, 0);
        issue(ra1, rw1, BK);
        lwrite(ra0, rw0, L + 0, L + 4096);

#pragma unroll 1
        for (int t = 0; t < nt; t += 2) {
            __syncthreads();
            domfma(L + 0, L + 4096);
            if (t + 2 < nt) issue(ra0, rw0, (t + 2) * BK);
            lwrite(ra1, rw1, L + 2048, L + 20480);      // tile t+1 (nt even)
            __syncthreads();
            domfma(L + 2048, L + 20480);
            if (t + 3 < nt) issue(ra1, rw1, (t + 3) * BK);
            if (t + 2 < nt) lwrite(ra0, rw0, L + 0, L + 4096);
        }
        __syncthreads();   // MFMAs done; LDS free for seq overlay

        // ---- epilogue: PreL = acc + bias; stage lwf bf16 (tri-zeroed) -----
        {
            float* PreL = (float*)L;
            float bv0 = bias[j0 + n0];
            float bv1 = bias[j0 + n1];
#pragma unroll
            for (int r = 0; r < 4; ++r) {
                PreL[(fq * 4 + r) * PLS + n0] = acc0[r] + bv0;
                PreL[(fq * 4 + r) * PLS + n1] = acc1[r] + bv1;
            }
            short* lw = (short*)(L + LWF_OFF);
            int u = tid & 127, th = tid >> 7;
            const short* wr_ = Wbf + (size_t)(j0 + u) * P_DIM + IN_DIM + j0 + th * 64;
#pragma unroll
            for (int s8 = 0; s8 < 8; ++s8) {
                short8 v = *(const short8*)(wr_ + s8 * 8);
#pragma unroll
                for (int e = 0; e < 8; ++e) {
                    int tt = th * 64 + s8 * 8 + e;
                    lw[tt * LWS + u] = (u > tt) ? v[e] : (short)0;
                }
            }
        }
        __syncthreads();

        // ---- read PreL into seq registers ----
        float as[8];
        {
            const float* pr = (const float*)L + srow * PLS + sl * 8;
            f32x4 v0 = *(const f32x4*)pr;
            f32x4 v1 = *(const f32x4*)(pr + 4);
            as[0] = v0[0]; as[1] = v0[1]; as[2] = v0[2]; as[3] = v0[3];
            as[4] = v1[0]; as[5] = v1[1]; as[6] = v1[2]; as[7] = v1[3];
        }

        // ---- 128 sequential steps; 1 ds_read + 1 shfl per step ----
        const short* lwf = (const short*)(L + LWF_OFF);
#pragma unroll 1
        for (int g = 0; g < 16; ++g) {
            const int hsrc = r4 | (g << 2);
            const bool own = (sl == g);
#pragma unroll
            for (int s = 0; s < 8; ++s) {
                const int t = g * 8 + s;
                short8 wv = *(const short8*)(lwf + t * LWS + sl * 8);
                float th_ = tanh_fast(as[s]);
                float h = __shfl(th_, hsrc);
                if (own) as[s] = th_;
#pragma unroll
                for (int e = 0; e < 8; ++e) {
                    float wf = __uint_as_float(((u32)(unsigned short)wv[e]) << 16);
                    as[e] += wf * h;
                }
            }
        }

        // ---- write h to global H panel / output ----
        if (J < 9) {
            short8 hv;
#pragma unroll
            for (int e = 0; e < 8; ++e) hv[e] = f2bf(as[e]);
            *(short8*)(Hg + (size_t)(bm + srow) * HG_COLS + j0 + sl * 8) = hv;
        }
        if (J >= 8) {
            float* op = out + (size_t)(bm + srow) * OUT_DIM + (j0 - IN_DIM) + sl * 8;
            float4 o0, o1;
            o0.x = sigmoid_fast(as[0]); o0.y = sigmoid_fast(as[1]);
            o0.z = sigmoid_fast(as[2]); o0.w = sigmoid_fast(as[3]);
            o1.x = sigmoid_fast(as[4]); o1.y = sigmoid_fast(as[5]);
            o1.z = sigmoid_fast(as[6]); o1.w = sigmoid_fast(as[7]);
            *(float4*)op = o0;
            *(float4*)(op + 4) = o1;
        }
    }
}

extern "C" void kernel_launch(void* const* d_in, const int* in_sizes, int n_in,
                              void* d_out, int out_size, void* d_ws, size_t ws_size,
                              hipStream_t stream)
{
    const float* x    = (const float*)d_in[0];
    const float* W    = (const float*)d_in[1];
    const float* bias = (const float*)d_in[2];
    float* out = (float*)d_out;
    short* Xbf = (short*)d_ws;
    short* Wbf = (short*)((char*)d_ws + WBF_OFF);
    short* Hg  = (short*)((char*)d_ws + HG_OFF);

    convert_x<<<dim3(B_ROWS * IN_DIM / 8 / 256), dim3(256), 0, stream>>>(x, Xbf);
    convert_w<<<dim3(M_DIM * P_DIM / 8 / 256), dim3(256), 0, stream>>>(W, Wbf);
    fused<<<dim3(B_ROWS / RB), dim3(256), 0, stream>>>(Xbf, Wbf, Hg, bias, out);
}

// Round 15
// 294.418 us; speedup vs baseline: 1.2813x; 1.0339x over previous
//
#include <hip/hip_runtime.h>
#include <hip/hip_bf16.h>
#include <math.h>

typedef short short8 __attribute__((ext_vector_type(8)));
typedef float f32x4  __attribute__((ext_vector_type(4)));
typedef unsigned int u32;

#define B_ROWS 8192
#define IN_DIM 1024
#define OUT_DIM 256
#define M_DIM 1280
#define P_DIM 2304
#define NJ 10
#define RB 16                  // rows per block -> 512 blocks, 2 blocks/CU
#define BK 64
#define HG_COLS 1152

// ws: Xbf bf16[8192][1024] ; Wbf bf16[1280][2304] ; Hg bf16[8192][1152]
#define WBF_OFF (B_ROWS * (size_t)IN_DIM * 2)
#define HG_OFF  (WBF_OFF + (size_t)M_DIM * P_DIM * 2)

__device__ __forceinline__ short f2bf(float x)
{
    __hip_bfloat16 h = __float2bfloat16(x);
    return *(short*)&h;
}

// tanh = 1 - 2/(e^{2x}+1); saturates correctly at +-inf.
__device__ __forceinline__ float tanh_fast(float x)
{
    float e = __expf(2.f * x);
    return 1.f - 2.f * __builtin_amdgcn_rcpf(e + 1.f);
}

__device__ __forceinline__ float sigmoid_fast(float y)
{
    return __builtin_amdgcn_rcpf(1.f + __expf(-y));
}

__device__ __forceinline__ float rdlane(float v, int l)
{
    return __int_as_float(__builtin_amdgcn_readlane(__float_as_int(v), l));
}

// barrier with LDS drain only -- in-flight GLOBAL loads stay in flight
// (avoids __syncthreads' forced s_waitcnt vmcnt(0)).
__device__ __forceinline__ void bar_lgkm()
{
    asm volatile("s_waitcnt lgkmcnt(0)" ::: "memory");
    __builtin_amdgcn_s_barrier();
}

__global__ __launch_bounds__(256)
void convert_x(const float* __restrict__ x, short* __restrict__ Xbf)
{
    int idx = blockIdx.x * 256 + threadIdx.x;
    int r  = idx >> 7;
    int c8 = (idx & 127) << 3;
    const float* src = x + (size_t)r * IN_DIM + c8;
    float4 a0 = *(const float4*)src;
    float4 a1 = *(const float4*)(src + 4);
    short8 s;
    s[0] = f2bf(a0.x); s[1] = f2bf(a0.y); s[2] = f2bf(a0.z); s[3] = f2bf(a0.w);
    s[4] = f2bf(a1.x); s[5] = f2bf(a1.y); s[6] = f2bf(a1.z); s[7] = f2bf(a1.w);
    *(short8*)(Xbf + (size_t)r * IN_DIM + c8) = s;
}

__global__ __launch_bounds__(256)
void convert_w(const float* __restrict__ W, short* __restrict__ Wbf)
{
    size_t e8 = ((size_t)blockIdx.x * 256 + threadIdx.x) * 8;
    float4 a0 = *(const float4*)(W + e8);
    float4 a1 = *(const float4*)(W + e8 + 4);
    short8 s;
    s[0] = f2bf(a0.x); s[1] = f2bf(a0.y); s[2] = f2bf(a0.z); s[3] = f2bf(a0.w);
    s[4] = f2bf(a1.x); s[5] = f2bf(a1.y); s[6] = f2bf(a1.z); s[7] = f2bf(a1.w);
    *(short8*)(Wbf + e8) = s;
}

// LDS union (43,264 B):
//  GEMM: xbuf[2] @0/@2048 (16x64 bf16, XOR-swz) ; wbuf[2] @4096/@20480 (128x64)
//  seq : PreL f32[16][132] @0 (8,448) ; lwf bf16[128][136] @8448 (34,816)
#define LWF_OFF 8448
#define PLS 132
#define LWS 136

__global__ __launch_bounds__(256, 2)
void fused(const short* __restrict__ Xbf, const short* __restrict__ Wbf,
           short* __restrict__ Hg, const float* __restrict__ bias,
           float* __restrict__ out)
{
    __shared__ __align__(16) char L[43264];

    const int tid  = threadIdx.x;
    const int lane = tid & 63;
    const int w    = tid >> 6;      // wave 0..3
    const int fr   = lane & 15;     // GEMM fragment row/col
    const int fq   = lane >> 4;     // GEMM k-quarter
    const int r4   = lane & 3;      // seq: row within wave's 4
    const int sl   = lane >> 2;     // seq: slice 0..15 (8 u's)
    const int srow = w * 4 + r4;    // seq row in block
    const int bm   = blockIdx.x * RB;
    const int sa_r  = tid >> 3;         // A staging (tid<128)
    const int sa_k8 = (tid & 7) << 3;
    const int n0 = w * 32 + fr;
    const int n1 = n0 + 16;

#pragma unroll 1
    for (int J = 0; J < NJ; ++J) {
        const int j0 = J * 128;
        const int nt = (IN_DIM + j0) / BK;   // 16 + 2J, always even

        f32x4 acc0 = {0.f, 0.f, 0.f, 0.f};
        f32x4 acc1 = {0.f, 0.f, 0.f, 0.f};

        __syncthreads();   // prev J fully done (lwf/PreL reads finished)

        auto issue = [&](short8& ra, short8 (&rw)[4], int k0) {
            if (tid < 128) {
                const short* s = (k0 < IN_DIM)
                    ? (Xbf + (size_t)(bm + sa_r) * IN_DIM + k0 + sa_k8)
                    : (Hg + (size_t)(bm + sa_r) * HG_COLS + (k0 - IN_DIM) + sa_k8);
                ra = *(const short8*)s;
            }
#pragma unroll
            for (int c = 0; c < 4; ++c) {
                int idx = tid + c * 256;
                int n = idx >> 3, k8 = (idx & 7) << 3;
                rw[c] = *(const short8*)(Wbf + (size_t)(j0 + n) * P_DIM + k0 + k8);
            }
        };
        auto lwrite = [&](short8& ra, short8 (&rw)[4], char* xw, char* ww) {
            if (tid < 128)
                *(short8*)(xw + ((sa_r * 128 + sa_k8 * 2) ^ ((sa_r & 7) << 4))) = ra;
#pragma unroll
            for (int c = 0; c < 4; ++c) {
                int idx = tid + c * 256;
                int n = idx >> 3, k8 = (idx & 7) << 3;
                *(short8*)(ww + ((n * 128 + k8 * 2) ^ ((n & 7) << 4))) = rw[c];
            }
        };
        auto domfma = [&](const char* xb, const char* wb) {
#pragma unroll
            for (int k32 = 0; k32 < 2; ++k32) {
                int kb = k32 * 64 + fq * 16;
                short8 a  = *(const short8*)(xb + ((fr * 128 + kb) ^ ((fr & 7) << 4)));
                short8 b0 = *(const short8*)(wb + ((n0 * 128 + kb) ^ ((n0 & 7) << 4)));
                short8 b1 = *(const short8*)(wb + ((n1 * 128 + kb) ^ ((n1 & 7) << 4)));
                acc0 = __builtin_amdgcn_mfma_f32_16x16x32_bf16(a, b0, acc0, 0, 0, 0);
                acc1 = __builtin_amdgcn_mfma_f32_16x16x32_bf16(a, b1, acc1, 0, 0, 0);
            }
        };

        // ---- GEMM: depth-2 register pipeline, counted-vmcnt barriers ------
        short8 ra0, ra1; short8 rw0[4], rw1[4];
        issue(ra0, rw0, 0);
        issue(ra1, rw1, BK);
        lwrite(ra0, rw0, L + 0, L + 4096);       // waits ra0 only (counted)

#pragma unroll 1
        for (int t = 0; t < nt; t += 2) {
            bar_lgkm();                          // buf0 visible; loads fly on
            if (t + 2 < nt) issue(ra0, rw0, (t + 2) * BK);
            domfma(L + 0, L + 4096);
            lwrite(ra1, rw1, L + 2048, L + 20480);
            bar_lgkm();                          // buf1 visible
            if (t + 3 < nt) issue(ra1, rw1, (t + 3) * BK);
            domfma(L + 2048, L + 20480);
            if (t + 2 < nt) lwrite(ra0, rw0, L + 0, L + 4096);
        }
        bar_lgkm();        // all MFMA ds_reads drained; LDS free for overlay

        // ---- epilogue: PreL = acc + bias; stage lwf bf16 (tri-zeroed) -----
        {
            float* PreL = (float*)L;
            float bv0 = bias[j0 + n0];
            float bv1 = bias[j0 + n1];
#pragma unroll
            for (int r = 0; r < 4; ++r) {
                PreL[(fq * 4 + r) * PLS + n0] = acc0[r] + bv0;
                PreL[(fq * 4 + r) * PLS + n1] = acc1[r] + bv1;
            }
            short* lw = (short*)(L + LWF_OFF);
            int u = tid & 127, th = tid >> 7;
            const short* wr_ = Wbf + (size_t)(j0 + u) * P_DIM + IN_DIM + j0 + th * 64;
#pragma unroll
            for (int s8 = 0; s8 < 8; ++s8) {
                short8 v = *(const short8*)(wr_ + s8 * 8);
#pragma unroll
                for (int e = 0; e < 8; ++e) {
                    int tt = th * 64 + s8 * 8 + e;
                    lw[tt * LWS + u] = (u > tt) ? v[e] : (short)0;
                }
            }
        }
        __syncthreads();

        // ---- read PreL into seq registers ----
        float as[8];
        {
            const float* pr = (const float*)L + srow * PLS + sl * 8;
            f32x4 v0 = *(const f32x4*)pr;
            f32x4 v1 = *(const f32x4*)(pr + 4);
            as[0] = v0[0]; as[1] = v0[1]; as[2] = v0[2]; as[3] = v0[3];
            as[4] = v1[0]; as[5] = v1[1]; as[6] = v1[2]; as[7] = v1[3];
        }

        // ---- 128 seq steps: ds_read + readlane broadcast (no DS on chain) -
        const short* lwf = (const short*)(L + LWF_OFF);
#pragma unroll 1
        for (int g = 0; g < 16; ++g) {
            const int  base = g << 2;
            const bool own  = (sl == g);
#pragma unroll
            for (int s = 0; s < 8; ++s) {
                const int t = g * 8 + s;
                short8 wv = *(const short8*)(lwf + t * LWS + sl * 8);
                float th_ = tanh_fast(as[s]);
                float b0 = rdlane(th_, base + 0);
                float b1 = rdlane(th_, base + 1);
                float b2 = rdlane(th_, base + 2);
                float b3 = rdlane(th_, base + 3);
                float h01 = (r4 & 1) ? b1 : b0;
                float h23 = (r4 & 1) ? b3 : b2;
                float h = (r4 & 2) ? h23 : h01;
                if (own) as[s] = th_;
#pragma unroll
                for (int e = 0; e < 8; ++e) {
                    float wf = __uint_as_float(((u32)(unsigned short)wv[e]) << 16);
                    as[e] += wf * h;
                }
            }
        }

        // ---- write h to global H panel / output ----
        if (J < 9) {
            short8 hv;
#pragma unroll
            for (int e = 0; e < 8; ++e) hv[e] = f2bf(as[e]);
            *(short8*)(Hg + (size_t)(bm + srow) * HG_COLS + j0 + sl * 8) = hv;
        }
        if (J >= 8) {
            float* op = out + (size_t)(bm + srow) * OUT_DIM + (j0 - IN_DIM) + sl * 8;
            float4 o0, o1;
            o0.x = sigmoid_fast(as[0]); o0.y = sigmoid_fast(as[1]);
            o0.z = sigmoid_fast(as[2]); o0.w = sigmoid_fast(as[3]);
            o1.x = sigmoid_fast(as[4]); o1.y = sigmoid_fast(as[5]);
            o1.z = sigmoid_fast(as[6]); o1.w = sigmoid_fast(as[7]);
            *(float4*)op = o0;
            *(float4*)(op + 4) = o1;
        }
    }
}

extern "C" void kernel_launch(void* const* d_in, const int* in_sizes, int n_in,
                              void* d_out, int out_size, void* d_ws, size_t ws_size,
                              hipStream_t stream)
{
    const float* x    = (const float*)d_in[0];
    const float* W    = (const float*)d_in[1];
    const float* bias = (const float*)d_in[2];
    float* out = (float*)d_out;
    short* Xbf = (short*)d_ws;
    short* Wbf = (short*)((char*)d_ws + WBF_OFF);
    short* Hg  = (short*)((char*)d_ws + HG_OFF);

    convert_x<<<dim3(B_ROWS * IN_DIM / 8 / 256), dim3(256), 0, stream>>>(x, Xbf);
    convert_w<<<dim3(M_DIM * P_DIM / 8 / 256), dim3(256), 0, stream>>>(W, Wbf);
    fused<<<dim3(B_ROWS / RB), dim3(256), 0, stream>>>(Xbf, Wbf, Hg, bias, out);
}

// Round 17
// 277.801 us; speedup vs baseline: 1.3579x; 1.0598x over previous
//
#include <hip/hip_runtime.h>
#include <hip/hip_bf16.h>
#include <math.h>

typedef short short8 __attribute__((ext_vector_type(8)));
typedef float f32x4  __attribute__((ext_vector_type(4)));
typedef float f32x2  __attribute__((ext_vector_type(2)));
typedef unsigned int u32;

#define B_ROWS 8192
#define IN_DIM 1024
#define OUT_DIM 256
#define M_DIM 1280
#define P_DIM 2304
#define NJ 10
#define RB 16                  // rows per block -> 512 blocks, 2 blocks/CU
#define BK 64
#define HG_COLS 1152

// ws: Xbf bf16[8192][1024] ; Wbf bf16[1280][2304] ; Hg bf16[8192][1152]
#define WBF_OFF (B_ROWS * (size_t)IN_DIM * 2)
#define HG_OFF  (WBF_OFF + (size_t)M_DIM * P_DIM * 2)

__device__ __forceinline__ short f2bf(float x)
{
    __hip_bfloat16 h = __float2bfloat16(x);
    return *(short*)&h;
}

// tanh = 1 - 2/(e^{2x}+1); saturates correctly at +-inf.
__device__ __forceinline__ float tanh_fast(float x)
{
    float e = __expf(2.f * x);
    return 1.f - 2.f * __builtin_amdgcn_rcpf(e + 1.f);
}

__device__ __forceinline__ float sigmoid_fast(float y)
{
    return __builtin_amdgcn_rcpf(1.f + __expf(-y));
}

// packed dual-f32 FMA: d = w * (h.lo broadcast) + d   (op_sel_hi: hi op reads src1.lo)
__device__ __forceinline__ void pk_fma_bcast(f32x2& d, f32x2 w, f32x2 h)
{
    asm("v_pk_fma_f32 %0, %1, %2, %0 op_sel_hi:[1,0,1]"
        : "+v"(d) : "v"(w), "v"(h));
}

// barrier with LDS drain only -- in-flight GLOBAL loads stay in flight.
__device__ __forceinline__ void bar_lgkm()
{
    asm volatile("s_waitcnt lgkmcnt(0)" ::: "memory");
    __builtin_amdgcn_s_barrier();
}

__global__ __launch_bounds__(256)
void convert_x(const float* __restrict__ x, short* __restrict__ Xbf)
{
    int idx = blockIdx.x * 256 + threadIdx.x;
    int r  = idx >> 7;
    int c8 = (idx & 127) << 3;
    const float* src = x + (size_t)r * IN_DIM + c8;
    float4 a0 = *(const float4*)src;
    float4 a1 = *(const float4*)(src + 4);
    short8 s;
    s[0] = f2bf(a0.x); s[1] = f2bf(a0.y); s[2] = f2bf(a0.z); s[3] = f2bf(a0.w);
    s[4] = f2bf(a1.x); s[5] = f2bf(a1.y); s[6] = f2bf(a1.z); s[7] = f2bf(a1.w);
    *(short8*)(Xbf + (size_t)r * IN_DIM + c8) = s;
}

__global__ __launch_bounds__(256)
void convert_w(const float* __restrict__ W, short* __restrict__ Wbf)
{
    size_t e8 = ((size_t)blockIdx.x * 256 + threadIdx.x) * 8;
    float4 a0 = *(const float4*)(W + e8);
    float4 a1 = *(const float4*)(W + e8 + 4);
    short8 s;
    s[0] = f2bf(a0.x); s[1] = f2bf(a0.y); s[2] = f2bf(a0.z); s[3] = f2bf(a0.w);
    s[4] = f2bf(a1.x); s[5] = f2bf(a1.y); s[6] = f2bf(a1.z); s[7] = f2bf(a1.w);
    *(short8*)(Wbf + e8) = s;
}

// LDS union (80,128 B):
//  GEMM: xbuf[2] @0/@2048 (XOR-swz) ; wbuf[2] @4096/@20480 (ends 36,864)
//  seq : PreL f32[16][132] @0 (8,448) ; lwf f32[128][140] @8448 (71,680)
#define LWF_OFF 8448
#define PLS 132
#define LWS 140   // physical stride covers swizzled col range [0,139]

__global__ __launch_bounds__(256, 2)
void fused(const short* __restrict__ Xbf, const short* __restrict__ Wbf,
           const float* __restrict__ Wf, short* __restrict__ Hg,
           const float* __restrict__ bias, float* __restrict__ out)
{
    __shared__ __align__(16) char L[80128];

    const int tid  = threadIdx.x;
    const int lane = tid & 63;
    const int w    = tid >> 6;      // wave 0..3
    const int fr   = lane & 15;     // GEMM fragment row/col
    const int fq   = lane >> 4;     // GEMM k-quarter
    const int r4   = lane & 3;      // seq: row within wave's 4
    const int sl   = lane >> 2;     // seq: slice 0..15 (8 u's)
    const int srow = w * 4 + r4;    // seq row in block
    const int bm   = blockIdx.x * RB;
    const int sa_r  = tid >> 3;         // A staging (tid<128)
    const int sa_k8 = (tid & 7) << 3;
    const int n0 = w * 32 + fr;
    const int n1 = n0 + 16;
    const int colb = sl * 8 + ((sl >> 2) << 2);   // swizzled lwf col base

#pragma unroll 1
    for (int J = 0; J < NJ; ++J) {
        const int j0 = J * 128;
        const int nt = (IN_DIM + j0) / BK;   // 16 + 2J, always even

        f32x4 acc0 = {0.f, 0.f, 0.f, 0.f};
        f32x4 acc1 = {0.f, 0.f, 0.f, 0.f};

        __syncthreads();   // prev J fully done (lwf/PreL reads finished)

        auto issue = [&](short8& ra, short8 (&rw)[4], int k0) {
            if (tid < 128) {
                const short* s = (k0 < IN_DIM)
                    ? (Xbf + (size_t)(bm + sa_r) * IN_DIM + k0 + sa_k8)
                    : (Hg + (size_t)(bm + sa_r) * HG_COLS + (k0 - IN_DIM) + sa_k8);
                ra = *(const short8*)s;
            }
#pragma unroll
            for (int c = 0; c < 4; ++c) {
                int idx = tid + c * 256;
                int n = idx >> 3, k8 = (idx & 7) << 3;
                rw[c] = *(const short8*)(Wbf + (size_t)(j0 + n) * P_DIM + k0 + k8);
            }
        };
        auto lwrite = [&](short8& ra, short8 (&rw)[4], char* xw, char* ww) {
            if (tid < 128)
                *(short8*)(xw + ((sa_r * 128 + sa_k8 * 2) ^ ((sa_r & 7) << 4))) = ra;
#pragma unroll
            for (int c = 0; c < 4; ++c) {
                int idx = tid + c * 256;
                int n = idx >> 3, k8 = (idx & 7) << 3;
                *(short8*)(ww + ((n * 128 + k8 * 2) ^ ((n & 7) << 4))) = rw[c];
            }
        };
        auto domfma = [&](const char* xb, const char* wb) {
#pragma unroll
            for (int k32 = 0; k32 < 2; ++k32) {
                int kb = k32 * 64 + fq * 16;
                short8 a  = *(const short8*)(xb + ((fr * 128 + kb) ^ ((fr & 7) << 4)));
                short8 b0 = *(const short8*)(wb + ((n0 * 128 + kb) ^ ((n0 & 7) << 4)));
                short8 b1 = *(const short8*)(wb + ((n1 * 128 + kb) ^ ((n1 & 7) << 4)));
                acc0 = __builtin_amdgcn_mfma_f32_16x16x32_bf16(a, b0, acc0, 0, 0, 0);
                acc1 = __builtin_amdgcn_mfma_f32_16x16x32_bf16(a, b1, acc1, 0, 0, 0);
            }
        };

        // ---- GEMM: depth-2 register pipeline, counted-vmcnt barriers ------
        short8 ra0, ra1; short8 rw0[4], rw1[4];
        issue(ra0, rw0, 0);
        issue(ra1, rw1, BK);
        lwrite(ra0, rw0, L + 0, L + 4096);

#pragma unroll 1
        for (int t = 0; t < nt; t += 2) {
            bar_lgkm();
            if (t + 2 < nt) issue(ra0, rw0, (t + 2) * BK);
            domfma(L + 0, L + 4096);
            lwrite(ra1, rw1, L + 2048, L + 20480);
            bar_lgkm();
            if (t + 3 < nt) issue(ra1, rw1, (t + 3) * BK);
            domfma(L + 2048, L + 20480);
            if (t + 2 < nt) lwrite(ra0, rw0, L + 0, L + 4096);
        }
        bar_lgkm();        // all MFMA ds_reads drained; LDS free for overlay

        // ---- epilogue: PreL = acc + bias; stage lwf f32 (tri-zeroed) ------
        {
            float* PreL = (float*)L;
            float bv0 = bias[j0 + n0];
            float bv1 = bias[j0 + n1];
#pragma unroll
            for (int r = 0; r < 4; ++r) {
                PreL[(fq * 4 + r) * PLS + n0] = acc0[r] + bv0;
                PreL[(fq * 4 + r) * PLS + n1] = acc1[r] + bv1;
            }
            float* lwf = (float*)(L + LWF_OFF);
            int u = tid & 127, th = tid >> 7;
            int cu = u + ((u >> 5) << 2);     // swizzled physical col, [0,139]
#pragma unroll
            for (int it = 0; it < 16; ++it) {
                int t4 = (it * 2 + th) * 4;
                float4 v = *(const float4*)(Wf + (size_t)(j0 + u) * P_DIM + IN_DIM + j0 + t4);
                lwf[(t4 + 0) * LWS + cu] = (u > t4 + 0) ? v.x : 0.f;
                lwf[(t4 + 1) * LWS + cu] = (u > t4 + 1) ? v.y : 0.f;
                lwf[(t4 + 2) * LWS + cu] = (u > t4 + 2) ? v.z : 0.f;
                lwf[(t4 + 3) * LWS + cu] = (u > t4 + 3) ? v.w : 0.f;
            }
        }
        __syncthreads();

        // ---- read PreL into seq register pairs ----
        f32x2 a01, a23, a45, a67;
        {
            const float* pr = (const float*)L + srow * PLS + sl * 8;
            a01 = *(const f32x2*)pr;
            a23 = *(const f32x2*)(pr + 2);
            a45 = *(const f32x2*)(pr + 4);
            a67 = *(const f32x2*)(pr + 6);
        }

        // ---- 128 seq steps: 2 ds_read + shfl + 4 pk_fma per step ----------
        const float* lwb = (const float*)(L + LWF_OFF) + colb;
#pragma unroll 1
        for (int g = 0; g < 16; ++g) {
            const int  hsrc = r4 | (g << 2);
            const bool own  = (sl == g);
#pragma unroll
            for (int s = 0; s < 8; ++s) {
                const int t = g * 8 + s;
                f32x4 w0 = *(const f32x4*)(lwb + t * LWS);
                f32x4 w1 = *(const f32x4*)(lwb + t * LWS + 4);
                float ps;
                switch (s) {   // static extract of as[s]
                    case 0: ps = a01[0]; break; case 1: ps = a01[1]; break;
                    case 2: ps = a23[0]; break; case 3: ps = a23[1]; break;
                    case 4: ps = a45[0]; break; case 5: ps = a45[1]; break;
                    case 6: ps = a67[0]; break; default: ps = a67[1]; break;
                }
                float th_ = tanh_fast(ps);
                float h = __shfl(th_, hsrc);
                f32x2 hp; hp[0] = h; hp[1] = h;
                f32x2 p0; p0[0] = w0[0]; p0[1] = w0[1];
                f32x2 p1; p1[0] = w0[2]; p1[1] = w0[3];
                f32x2 p2; p2[0] = w1[0]; p2[1] = w1[1];
                f32x2 p3; p3[0] = w1[2]; p3[1] = w1[3];
                pk_fma_bcast(a01, p0, hp);
                pk_fma_bcast(a23, p1, hp);
                pk_fma_bcast(a45, p2, hp);
                pk_fma_bcast(a67, p3, hp);
                if (own) {     // weight[t][t]=0 left as[s]=preact; fix to h
                    switch (s) {
                        case 0: a01[0] = h; break; case 1: a01[1] = h; break;
                        case 2: a23[0] = h; break; case 3: a23[1] = h; break;
                        case 4: a45[0] = h; break; case 5: a45[1] = h; break;
                        case 6: a67[0] = h; break; default: a67[1] = h; break;
                    }
                }
            }
        }

        float as[8] = {a01[0], a01[1], a23[0], a23[1],
                       a45[0], a45[1], a67[0], a67[1]};

        // ---- write h to global H panel / output ----
        if (J < 9) {
            short8 hv;
#pragma unroll
            for (int e = 0; e < 8; ++e) hv[e] = f2bf(as[e]);
            *(short8*)(Hg + (size_t)(bm + srow) * HG_COLS + j0 + sl * 8) = hv;
        }
        if (J >= 8) {
            float* op = out + (size_t)(bm + srow) * OUT_DIM + (j0 - IN_DIM) + sl * 8;
            float4 o0, o1;
            o0.x = sigmoid_fast(as[0]); o0.y = sigmoid_fast(as[1]);
            o0.z = sigmoid_fast(as[2]); o0.w = sigmoid_fast(as[3]);
            o1.x = sigmoid_fast(as[4]); o1.y = sigmoid_fast(as[5]);
            o1.z = sigmoid_fast(as[6]); o1.w = sigmoid_fast(as[7]);
            *(float4*)op = o0;
            *(float4*)(op + 4) = o1;
        }
    }
}

extern "C" void kernel_launch(void* const* d_in, const int* in_sizes, int n_in,
                              void* d_out, int out_size, void* d_ws, size_t ws_size,
                              hipStream_t stream)
{
    const float* x    = (const float*)d_in[0];
    const float* W    = (const float*)d_in[1];
    const float* bias = (const float*)d_in[2];
    float* out = (float*)d_out;
    short* Xbf = (short*)d_ws;
    short* Wbf = (short*)((char*)d_ws + WBF_OFF);
    short* Hg  = (short*)((char*)d_ws + HG_OFF);

    convert_x<<<dim3(B_ROWS * IN_DIM / 8 / 256), dim3(256), 0, stream>>>(x, Xbf);
    convert_w<<<dim3(M_DIM * P_DIM / 8 / 256), dim3(256), 0, stream>>>(W, Wbf);
    fused<<<dim3(B_ROWS / RB), dim3(256), 0, stream>>>(Xbf, Wbf, W, Hg, bias, out);
}

// Round 18
// 236.011 us; speedup vs baseline: 1.5984x; 1.1771x over previous
//
#include <hip/hip_runtime.h>
#include <hip/hip_bf16.h>
#include <math.h>

typedef short short8 __attribute__((ext_vector_type(8)));
typedef float f32x4  __attribute__((ext_vector_type(4)));
typedef float f32x2  __attribute__((ext_vector_type(2)));
typedef unsigned int u32;

#define B_ROWS 8192
#define IN_DIM 1024
#define OUT_DIM 256
#define M_DIM 1280
#define P_DIM 2304
#define NJ 10
#define RB 32                  // rows per block -> 256 blocks, 1 block/CU, 8 waves
#define BK 128
#define HG_COLS 1152

// ws: Xbf bf16[8192][1024] ; Wbf bf16[1280][2304] ; Hg bf16[8192][1152]
#define WBF_OFF (B_ROWS * (size_t)IN_DIM * 2)
#define HG_OFF  (WBF_OFF + (size_t)M_DIM * P_DIM * 2)

__device__ __forceinline__ short f2bf(float x)
{
    __hip_bfloat16 h = __float2bfloat16(x);
    return *(short*)&h;
}

// tanh = 1 - 2/(e^{2x}+1); saturates correctly at +-inf.
__device__ __forceinline__ float tanh_fast(float x)
{
    float e = __expf(2.f * x);
    return 1.f - 2.f * __builtin_amdgcn_rcpf(e + 1.f);
}

__device__ __forceinline__ float sigmoid_fast(float y)
{
    return __builtin_amdgcn_rcpf(1.f + __expf(-y));
}

// packed dual-f32 FMA: d += w * h (h broadcast from lo)
__device__ __forceinline__ void pk_fma_bcast(f32x2& d, f32x2 w, f32x2 h)
{
    asm("v_pk_fma_f32 %0, %1, %2, %0 op_sel_hi:[1,0,1]"
        : "+v"(d) : "v"(w), "v"(h));
}

// barrier with LDS drain only -- in-flight GLOBAL loads stay in flight.
__device__ __forceinline__ void bar_lgkm()
{
    asm volatile("s_waitcnt lgkmcnt(0)" ::: "memory");
    __builtin_amdgcn_s_barrier();
}

__global__ __launch_bounds__(256)
void convert_x(const float* __restrict__ x, short* __restrict__ Xbf)
{
    int idx = blockIdx.x * 256 + threadIdx.x;
    int r  = idx >> 7;
    int c8 = (idx & 127) << 3;
    const float* src = x + (size_t)r * IN_DIM + c8;
    float4 a0 = *(const float4*)src;
    float4 a1 = *(const float4*)(src + 4);
    short8 s;
    s[0] = f2bf(a0.x); s[1] = f2bf(a0.y); s[2] = f2bf(a0.z); s[3] = f2bf(a0.w);
    s[4] = f2bf(a1.x); s[5] = f2bf(a1.y); s[6] = f2bf(a1.z); s[7] = f2bf(a1.w);
    *(short8*)(Xbf + (size_t)r * IN_DIM + c8) = s;
}

__global__ __launch_bounds__(256)
void convert_w(const float* __restrict__ W, short* __restrict__ Wbf)
{
    size_t e8 = ((size_t)blockIdx.x * 256 + threadIdx.x) * 8;
    float4 a0 = *(const float4*)(W + e8);
    float4 a1 = *(const float4*)(W + e8 + 4);
    short8 s;
    s[0] = f2bf(a0.x); s[1] = f2bf(a0.y); s[2] = f2bf(a0.z); s[3] = f2bf(a0.w);
    s[4] = f2bf(a1.x); s[5] = f2bf(a1.y); s[6] = f2bf(a1.z); s[7] = f2bf(a1.w);
    *(short8*)(Wbf + e8) = s;
}

// LDS union (88,576 B):
//  GEMM: xbuf[2] @0/@8192 (32x256B rows, XOR-swz) ; wbuf[2] @16384/@49152 (128x256B)
//  seq : PreL f32[32][132] @0 (16,896) ; lwf f32[128][140] @16896 (71,680)
#define XB0 0
#define XB1 8192
#define WB0 16384
#define WB1 49152
#define LWF_OFF 16896
#define PLS 132
#define LWS 140

__global__ __launch_bounds__(512, 1)
void fused(const short* __restrict__ Xbf, const short* __restrict__ Wbf,
           const float* __restrict__ Wf, short* __restrict__ Hg,
           const float* __restrict__ bias, float* __restrict__ out)
{
    __shared__ __align__(16) char L[88576];

    const int tid  = threadIdx.x;
    const int lane = tid & 63;
    const int w    = tid >> 6;      // wave 0..7
    const int fr   = lane & 15;     // fragment row/col
    const int fq   = lane >> 4;     // k-quarter / row-quad
    const int rh   = w & 1;         // GEMM row-half (16 rows)
    const int wc   = w >> 1;        // GEMM col-pair (32 cols)
    const int r4   = lane & 3;      // seq: row within wave's 4
    const int sl   = lane >> 2;     // seq: slice 0..15
    const int srow = w * 4 + r4;    // seq row 0..31
    const int bm   = blockIdx.x * RB;
    const int sa_r = tid >> 4;          // A staging row 0..31
    const int sa_c = (tid & 15) << 3;   // A staging col (shorts)
    const int n0 = wc * 32 + fr;
    const int n1 = n0 + 16;
    const int colb = sl * 8 + ((sl >> 2) << 2);   // swizzled lwf col base

#pragma unroll 1
    for (int J = 0; J < NJ; ++J) {
        const int j0 = J * 128;
        const int nt = (IN_DIM + j0) / BK;   // 8 + J

        f32x4 acc0 = {0.f, 0.f, 0.f, 0.f};
        f32x4 acc1 = {0.f, 0.f, 0.f, 0.f};

        __syncthreads();   // prev J fully done

        auto issue = [&](short8& ra, short8 (&rw)[4], int k0) {
            const short* s = (k0 < IN_DIM)
                ? (Xbf + (size_t)(bm + sa_r) * IN_DIM + k0 + sa_c)
                : (Hg + (size_t)(bm + sa_r) * HG_COLS + (k0 - IN_DIM) + sa_c);
            ra = *(const short8*)s;
#pragma unroll
            for (int c = 0; c < 4; ++c) {
                int idx = tid + c * 512;
                int n = idx >> 4, kc = (idx & 15) << 3;
                rw[c] = *(const short8*)(Wbf + (size_t)(j0 + n) * P_DIM + k0 + kc);
            }
        };
        auto lwrite = [&](short8& ra, short8 (&rw)[4], char* xw, char* ww) {
            *(short8*)(xw + ((sa_r * 256 + sa_c * 2) ^ ((sa_r & 15) << 4))) = ra;
#pragma unroll
            for (int c = 0; c < 4; ++c) {
                int idx = tid + c * 512;
                int n = idx >> 4, kc = (idx & 15) << 3;
                *(short8*)(ww + ((n * 256 + kc * 2) ^ ((n & 15) << 4))) = rw[c];
            }
        };
        auto domfma = [&](const char* xb, const char* wb) {
#pragma unroll
            for (int k32 = 0; k32 < 4; ++k32) {
                int kb = k32 * 64 + fq * 16;
                short8 a  = *(const short8*)(xb + (((rh * 16 + fr) * 256 + (kb ^ (fr << 4)))));
                short8 b0 = *(const short8*)(wb + ((n0 * 256 + (kb ^ (fr << 4)))));
                short8 b1 = *(const short8*)(wb + ((n1 * 256 + (kb ^ (fr << 4)))));
                acc0 = __builtin_amdgcn_mfma_f32_16x16x32_bf16(a, b0, acc0, 0, 0, 0);
                acc1 = __builtin_amdgcn_mfma_f32_16x16x32_bf16(a, b1, acc1, 0, 0, 0);
            }
        };

        // ---- GEMM: depth-2 register pipeline, counted-vmcnt barriers ------
        short8 ra0, ra1; short8 rw0[4], rw1[4];
        issue(ra0, rw0, 0);
        issue(ra1, rw1, BK);
        lwrite(ra0, rw0, L + XB0, L + WB0);

#pragma unroll 1
        for (int t = 0; t + 1 < nt; t += 2) {
            bar_lgkm();
            if (t + 2 < nt) issue(ra0, rw0, (t + 2) * BK);
            domfma(L + XB0, L + WB0);
            lwrite(ra1, rw1, L + XB1, L + WB1);
            bar_lgkm();
            if (t + 3 < nt) issue(ra1, rw1, (t + 3) * BK);
            domfma(L + XB1, L + WB1);
            if (t + 2 < nt) lwrite(ra0, rw0, L + XB0, L + WB0);
        }
        if (nt & 1) {          // peeled last tile (sits in buf0)
            bar_lgkm();
            domfma(L + XB0, L + WB0);
        }
        bar_lgkm();            // drain; LDS free for seq overlay

        // ---- epilogue: PreL = acc + bias; stage lwf f32 (tri-zeroed) ------
        {
            float* PreL = (float*)L;
            float bv0 = bias[j0 + n0];
            float bv1 = bias[j0 + n1];
#pragma unroll
            for (int r = 0; r < 4; ++r) {
                int row = rh * 16 + fq * 4 + r;
                PreL[row * PLS + n0] = acc0[r] + bv0;
                PreL[row * PLS + n1] = acc1[r] + bv1;
            }
            float* lwf = (float*)(L + LWF_OFF);
            int u = tid & 127, th = tid >> 7;     // th 0..3
            int cu = u + ((u >> 5) << 2);         // swizzled col, [0,139]
#pragma unroll
            for (int it = 0; it < 8; ++it) {
                int t4 = (it * 4 + th) * 4;
                float4 v = *(const float4*)(Wf + (size_t)(j0 + u) * P_DIM + IN_DIM + j0 + t4);
                lwf[(t4 + 0) * LWS + cu] = (u > t4 + 0) ? v.x : 0.f;
                lwf[(t4 + 1) * LWS + cu] = (u > t4 + 1) ? v.y : 0.f;
                lwf[(t4 + 2) * LWS + cu] = (u > t4 + 2) ? v.z : 0.f;
                lwf[(t4 + 3) * LWS + cu] = (u > t4 + 3) ? v.w : 0.f;
            }
        }
        __syncthreads();

        // ---- read PreL into seq register pairs ----
        f32x2 a01, a23, a45, a67;
        {
            const float* pr = (const float*)L + srow * PLS + sl * 8;
            a01 = *(const f32x2*)pr;
            a23 = *(const f32x2*)(pr + 2);
            a45 = *(const f32x2*)(pr + 4);
            a67 = *(const f32x2*)(pr + 6);
        }

        // ---- 128 seq steps: 2 ds_read + shfl + 4 pk_fma per step ----------
        const float* lwb = (const float*)(L + LWF_OFF) + colb;
#pragma unroll 1
        for (int g = 0; g < 16; ++g) {
            const int  hsrc = r4 | (g << 2);
            const bool own  = (sl == g);
#pragma unroll
            for (int s = 0; s < 8; ++s) {
                const int t = g * 8 + s;
                f32x4 w0 = *(const f32x4*)(lwb + t * LWS);
                f32x4 w1 = *(const f32x4*)(lwb + t * LWS + 4);
                float ps;
                switch (s) {
                    case 0: ps = a01[0]; break; case 1: ps = a01[1]; break;
                    case 2: ps = a23[0]; break; case 3: ps = a23[1]; break;
                    case 4: ps = a45[0]; break; case 5: ps = a45[1]; break;
                    case 6: ps = a67[0]; break; default: ps = a67[1]; break;
                }
                float th_ = tanh_fast(ps);
                float h = __shfl(th_, hsrc);
                f32x2 hp; hp[0] = h; hp[1] = h;
                f32x2 p0; p0[0] = w0[0]; p0[1] = w0[1];
                f32x2 p1; p1[0] = w0[2]; p1[1] = w0[3];
                f32x2 p2; p2[0] = w1[0]; p2[1] = w1[1];
                f32x2 p3; p3[0] = w1[2]; p3[1] = w1[3];
                pk_fma_bcast(a01, p0, hp);
                pk_fma_bcast(a23, p1, hp);
                pk_fma_bcast(a45, p2, hp);
                pk_fma_bcast(a67, p3, hp);
                if (own) {
                    switch (s) {
                        case 0: a01[0] = h; break; case 1: a01[1] = h; break;
                        case 2: a23[0] = h; break; case 3: a23[1] = h; break;
                        case 4: a45[0] = h; break; case 5: a45[1] = h; break;
                        case 6: a67[0] = h; break; default: a67[1] = h; break;
                    }
                }
            }
        }

        float as[8] = {a01[0], a01[1], a23[0], a23[1],
                       a45[0], a45[1], a67[0], a67[1]};

        // ---- write h to global H panel / output ----
        if (J < 9) {
            short8 hv;
#pragma unroll
            for (int e = 0; e < 8; ++e) hv[e] = f2bf(as[e]);
            *(short8*)(Hg + (size_t)(bm + srow) * HG_COLS + j0 + sl * 8) = hv;
        }
        if (J >= 8) {
            float* op = out + (size_t)(bm + srow) * OUT_DIM + (j0 - IN_DIM) + sl * 8;
            float4 o0, o1;
            o0.x = sigmoid_fast(as[0]); o0.y = sigmoid_fast(as[1]);
            o0.z = sigmoid_fast(as[2]); o0.w = sigmoid_fast(as[3]);
            o1.x = sigmoid_fast(as[4]); o1.y = sigmoid_fast(as[5]);
            o1.z = sigmoid_fast(as[6]); o1.w = sigmoid_fast(as[7]);
            *(float4*)op = o0;
            *(float4*)(op + 4) = o1;
        }
    }
}

extern "C" void kernel_launch(void* const* d_in, const int* in_sizes, int n_in,
                              void* d_out, int out_size, void* d_ws, size_t ws_size,
                              hipStream_t stream)
{
    const float* x    = (const float*)d_in[0];
    const float* W    = (const float*)d_in[1];
    const float* bias = (const float*)d_in[2];
    float* out = (float*)d_out;
    short* Xbf = (short*)d_ws;
    short* Wbf = (short*)((char*)d_ws + WBF_OFF);
    short* Hg  = (short*)((char*)d_ws + HG_OFF);

    convert_x<<<dim3(B_ROWS * IN_DIM / 8 / 256), dim3(256), 0, stream>>>(x, Xbf);
    convert_w<<<dim3(M_DIM * P_DIM / 8 / 256), dim3(256), 0, stream>>>(W, Wbf);
    fused<<<dim3(B_ROWS / RB), dim3(512), 0, stream>>>(Xbf, Wbf, W, Hg, bias, out);
}